// Round 17
// baseline (1301.043 us; speedup 1.0000x reference)
//
#include <hip/hip_runtime.h>
#include <hip/hip_bf16.h>

// R17: launch-count reduction (43 -> 22):
//  - finalize folded into conv via last-block-done (device counter; shard
//    re-read through atomic-RMW -> coherent); identical fp64 math
//  - t2/5/8 bnqpool + 3 pools merged into one poolcombo launch (grid.y = op)
//  - wt/qx/stats_init merged into one setup kernel
// conv main loop = R15 (R16 dbuf was neutral; revert to 45KB LDS).

typedef unsigned short u16;
typedef signed char i8;
typedef unsigned long long ull;
typedef long long ll;
typedef int i32x4 __attribute__((ext_vector_type(4)));

__device__ __forceinline__ void glds16(const i8* g, i8* l) {
    __builtin_amdgcn_global_load_lds(
        (const __attribute__((address_space(1))) void*)g,
        (__attribute__((address_space(3))) void*)l, 16, 0, 0);
}

__global__ void fill_kernel(float* __restrict__ out, int n, float v) {
    int i = blockIdx.x * 256 + threadIdx.x;
    if (i < n) out[i] = v;
}

// merged setup: wt (blocks 0..143), qx (144..8855), stats+ctr init (8856..9015)
__global__ void setup_kernel(const float* __restrict__ w, i8* __restrict__ wt,
                             const float* __restrict__ x, i8* __restrict__ qout,
                             ull* s1, ull* s2, int* kmn, int* kmx, unsigned* ctr) {
    int b = blockIdx.x;
    int tid = threadIdx.x;
    if (b < 144) {
        int g = b * 256 + tid;                      // 36864 groups of 16
        int base = g * 16;
        int ci0 = base & 255;
        int co  = (base >> 8) & 255;
        int tap = base >> 16;
        i8 tmp[16];
#pragma unroll
        for (int j = 0; j < 16; j++)
            tmp[j] = (i8)__builtin_rintf(w[((co << 8) + ci0 + j) * 9 + tap] * 64.0f);
        *(uint4*)(wt + base) = *(const uint4*)tmp;
    } else if (b < 8856) {
        int g = (b - 144) * 256 + tid;              // halo-padded 66x66 qx
        int chunk = g & 15;
        int p = g >> 4;
        i8 tmp[16];
#pragma unroll
        for (int j = 0; j < 16; j++) tmp[j] = 0;
        if (chunk == 0) {
            int n  = p / 4356;
            int pp = p - n * 4356;
            int py = pp / 66;
            int px = pp - py * 66;
            if (py >= 1 && py <= 64 && px >= 1 && px <= 64) {
                int yx = ((py - 1) << 6) + (px - 1);
#pragma unroll
                for (int c = 0; c < 3; c++)
                    tmp[c] = (i8)truncf(x[((n * 3 + c) << 12) + yx] * (1.0f / 64.0f));
            }
        }
        *(uint4*)(qout + (size_t)g * 16) = *(const uint4*)tmp;
    } else {
        int i = (b - 8856) * 256 + tid;             // 40960 stat slots
        s1[i] = 0ull; s2[i] = 0ull;
        kmn[i] = 0x7fffffff; kmx[i] = -0x7fffffff - 1;
        if (i < 16) ctr[i] = 0u;
    }
}

// conv 3x3 implicit GEMM, i8 MFMA K=64; A halo-band + 3-tap B groups (R15),
// fused epilogue + LAST-BLOCK finalize (mu/rs/invv).
template<int NH>
__global__ __launch_bounds__(256) void conv_kernel(
    const i8* __restrict__ act, const i8* __restrict__ wtp, int* __restrict__ a_pre,
    const i8* __restrict__ h0, const i8* __restrict__ h1,
    const i8* __restrict__ h2, const i8* __restrict__ h3,
    const float* __restrict__ alphas, int t,
    int W, int logW, int PW, int nA, int M,
    const float* __restrict__ g1, const float* __restrict__ g2,
    ull* __restrict__ s1g, ull* __restrict__ s2g,
    int* __restrict__ kmng, int* __restrict__ kmxg,
    double* __restrict__ mu_o, double* __restrict__ rs_o, float* __restrict__ invv,
    unsigned* __restrict__ ctr)
{
    __shared__ __align__(16) i8 As[320 * 64];      // A halo band (one ci-chunk)
    __shared__ __align__(16) i8 Bs[3 * 128 * 64];  // B, 3 taps
    __shared__ int lastFlag;
    const int tid  = threadIdx.x;
    const int G    = gridDim.x;
    const int d    = blockIdx.x;
    const int sw   = (d & 7) * (G >> 3) + (d >> 3);   // XCD-contiguous
    const int m0   = (sw >> 1) * 128;
    const int c0   = (sw & 1) * 128;
    const int lane = tid & 63;
    const int wv   = tid >> 6;
    const int wm   = (wv & 1) * 64;
    const int wn   = (wv >> 1) * 64;
    const int l15  = lane & 15;
    const int quad = lane >> 4;
    const int logHW = 2 * logW;
    const int HW   = W * W;
    const int PP   = PW * PW;

    i32x4 acc[4][4];
#pragma unroll
    for (int i = 0; i < 4; i++)
#pragma unroll
        for (int j = 0; j < 4; j++) acc[i][j] = (i32x4){0, 0, 0, 0};

    const int n0 = m0 >> logHW;
    const int y0 = (m0 & (HW - 1)) >> logW;
    const long bandstart = (long)n0 * PP + (long)y0 * PW;

    int pb[4];
#pragma unroll
    for (int i = 0; i < 4; i++) {
        int mr = m0 + wm + i * 16 + l15;
        int nn = mr >> logHW;
        int rr = mr & (HW - 1);
        pb[i] = (nn - n0) * PP + ((rr >> logW) - y0 + 1) * PW + (rr & (W - 1)) + 1;
    }

    const int qrow = tid >> 2;                      // 0..63
    const int bb   = (tid & 3) * 16;
    i8* const ldsbaseA = As + wv * 1024 + lane * 16;
    const int ko = quad * 16;

    for (int chunk = 0; chunk < 4; ++chunk) {
        const int cb = chunk * 64;
#pragma unroll
        for (int g = 0; g < 3; ++g) {
            __syncthreads();                        // prev readers done
            if (g == 0) {
                for (int k = 0; k < nA; ++k)        // stage A band
                    glds16(act + (bandstart + qrow + k * 64) * 256 + cb + bb,
                           ldsbaseA + k * 4096);
            }
#pragma unroll
            for (int tt = 0; tt < 3; ++tt) {        // stage B taps 3g..3g+2
                const int tap = 3 * g + tt;
#pragma unroll
                for (int p = 0; p < 2; ++p)
                    glds16(wtp + (tap << 16) + ((c0 + qrow + p * 64) << 8) + cb + bb,
                           Bs + tt * 8192 + wv * 1024 + p * 4096 + lane * 16);
            }
            __syncthreads();                        // DMA drained
#pragma unroll
            for (int tt = 0; tt < 3; ++tt) {
                const int tap = 3 * g + tt;
                const int dY  = tap / 3 - 1;
                const int dX  = tap % 3 - 1;
                const int uoff = dY * PW + dX;
                i32x4 bf[4];
#pragma unroll
                for (int j = 0; j < 4; j++)
                    bf[j] = *(const i32x4*)(&Bs[tt * 8192 + (wn + j * 16 + l15) * 64 + ko]);
#pragma unroll
                for (int i = 0; i < 4; i++) {
                    i32x4 af = *(const i32x4*)(&As[(pb[i] + uoff) * 64 + ko]);
#pragma unroll
                    for (int j = 0; j < 4; j++)
                        acc[i][j] = __builtin_amdgcn_mfma_i32_16x16x64_i8(af, bf[j], acc[i][j], 0, 0, 0);
                }
            }
        }
    }

    // epilogue: a_k = a0k*relu(K) + 64*sum(aqk*hk)
    const int a0k = (int)__builtin_rintf(alphas[t * 6] * 64.0f);
    int aq64[NH];
    const i8* hp[4] = {h0, h1, h2, h3};
#pragma unroll
    for (int q = 0; q < NH; q++)
        aq64[q] = (int)__builtin_rintf(alphas[t * 6 + (6 - NH) + q] * 64.0f) * 64;

    const int shard = sw & 15;
#pragma unroll
    for (int j = 0; j < 4; j++) {
        const int cg = c0 + wn + j * 16 + l15;
        ll s1 = 0, s2 = 0;
        int mn = 0x7fffffff, mx = -0x7fffffff - 1;
#pragma unroll
        for (int i = 0; i < 4; i++) {
            const int mo0 = m0 + wm + i * 16 + quad * 4;
            const int n   = mo0 >> logHW;
            const int rem = mo0 & (HW - 1);
            const int yy  = rem >> logW;
            const int xx  = rem & (W - 1);
            const int phb = (((n * PW + yy + 1) * PW) + xx + 1) << 8;
#pragma unroll
            for (int r = 0; r < 4; r++) {
                const int idx  = ((mo0 + r) << 8) + cg;
                const int pidx = phb + (r << 8) + cg;
                int K = acc[i][j][r];
                int av = a0k * (K > 0 ? K : 0);
#pragma unroll
                for (int q = 0; q < NH; q++) av += aq64[q] * (int)hp[q][pidx];
                a_pre[idx] = av;
                s1 += av;
                s2 += (ll)av * (ll)av;
                mn = av < mn ? av : mn;
                mx = av > mx ? av : mx;
            }
        }
        s1 += __shfl_xor(s1, 16); s1 += __shfl_xor(s1, 32);
        s2 += __shfl_xor(s2, 16); s2 += __shfl_xor(s2, 32);
        int o;
        o = __shfl_xor(mn, 16); mn = o < mn ? o : mn;
        o = __shfl_xor(mn, 32); mn = o < mn ? o : mn;
        o = __shfl_xor(mx, 16); mx = o > mx ? o : mx;
        o = __shfl_xor(mx, 32); mx = o > mx ? o : mx;
        if (quad == 0) {
            const int sidx = shard * 2560 + t * 256 + cg;
            atomicAdd(&s1g[sidx], (ull)s1);
            atomicAdd(&s2g[sidx], (ull)s2);
            atomicMin(&kmng[sidx], mn);
            atomicMax(&kmxg[sidx], mx);
        }
    }

    // last-block finalize (all block atomics drained by the barrier's vmcnt(0))
    __syncthreads();
    if (tid == 0) {
        __threadfence();
        unsigned old = atomicAdd(&ctr[t], 1u);
        lastFlag = (old == (unsigned)(G - 1)) ? 1 : 0;
    }
    __syncthreads();
    if (lastFlag) {
        const int c = tid;
        const float* Gm = (g1[0] >= 32.0f) ? g1 : g2;
        const float* Bt = (g1[0] >= 32.0f) ? g2 : g1;
        ll S1i = 0, S2i = 0;
        int kmn = 0x7fffffff, kmx = -0x7fffffff - 1;
        for (int sh = 0; sh < 16; sh++) {
            int sidx = sh * 2560 + t * 256 + c;
            S1i += (ll)atomicAdd(&s1g[sidx], 0ull);         // coherent read
            S2i += (ll)atomicAdd(&s2g[sidx], 0ull);
            int a = atomicMin(&kmng[sidx], 0x7fffffff);     // returns old, no-op write
            kmn = a < kmn ? a : kmn;
            int b2 = atomicMax(&kmxg[sidx], -0x7fffffff - 1);
            kmx = b2 > kmx ? b2 : kmx;
        }
        double S1 = (double)S1i;
        double S2 = (double)S2i;
        double Md = (double)M;
        double mu = S1 / (Md * 262144.0);
        double var = (S2 - S1 * S1 / Md) / (Md * 68719476736.0);
        if (var < 0.0) var = 0.0;
        double rs = 1.0 / sqrt(var + 1e-5);
        mu_o[c] = mu; rs_o[c] = rs;
        double g = (double)Gm[t * 256 + c];
        double b = (double)Bt[t * 256 + c];
        double lo = (double)kmn * (1.0 / 262144.0);
        double hi = (double)kmx * (1.0 / 262144.0);
        double bnlo = g * ((lo - mu) * rs) + b;
        double bnhi = g * ((hi - mu) * rs) + b;
        float* red = (float*)As;                    // reuse LDS (main loop done)
        red[c] = (float)fmax(fabs(bnlo), fabs(bnhi));
        __syncthreads();
        for (int s = 128; s > 0; s >>= 1) {
            if (c < s) red[c] = fmaxf(red[c], red[c + s]);
            __syncthreads();
        }
        if (c == 0) invv[0] = (red[0] < 1.0f) ? (1.0f / 128.0f) : (1.0f / 64.0f);
    }
}

// BN apply + quantize -> padded int8 (halo = 0); dense a_pre in
__global__ void bnq_kernel(const int* __restrict__ a, i8* __restrict__ out,
                           const double* __restrict__ mu, const double* __restrict__ rs,
                           const float* __restrict__ g1, const float* __restrict__ g2,
                           int t, const float* __restrict__ invv,
                           int W, int logW, int PW) {
    int c = threadIdx.x;
    int sp = blockIdx.x;
    int PP = PW * PW;
    int n  = sp / PP;
    int pp = sp - n * PP;
    int py = pp / PW;
    int px = pp - py * PW;
    int y = py - 1, x = px - 1;
    i8 v = 0;
    if ((unsigned)y < (unsigned)W && (unsigned)x < (unsigned)W) {
        const float* G = (g1[0] >= 32.0f) ? g1 : g2;
        const float* B = (g1[0] >= 32.0f) ? g2 : g1;
        double m = mu[c], r = rs[c];
        double g = (double)G[t * 256 + c];
        double b = (double)B[t * 256 + c];
        double iv = (double)invv[0];
        int idx = (((n << logW) + y) << logW << 8) + (x << 8) + c;
        double bn = g * (((double)a[idx] * (1.0 / 262144.0) - m) * r) + b;
        v = (i8)(int)trunc(bn * iv);
    }
    out[((size_t)sp << 8) + c] = v;
}

// merged pool step: grid.y==0 -> fused BN+quantize+2x2maxpool (a_pre -> bq_out);
// grid.y==1..3 -> plain 2x2 maxpool (pi -> po). All padded layout (halo=0).
__global__ void poolcombo_kernel(const int* __restrict__ a, i8* __restrict__ bq_out,
                                 const i8* __restrict__ pi1, i8* __restrict__ po1,
                                 const i8* __restrict__ pi2, i8* __restrict__ po2,
                                 const i8* __restrict__ pi3, i8* __restrict__ po3,
                                 const double* __restrict__ mu, const double* __restrict__ rs,
                                 const float* __restrict__ g1, const float* __restrict__ g2,
                                 int t, const float* __restrict__ invv, int Dout) {
    int c = threadIdx.x;
    int sp = blockIdx.x;
    int op = blockIdx.y;
    int P = Dout + 2;
    int PP = P * P;
    int n  = sp / PP;
    int pp = sp - n * PP;
    int py = pp / P;
    int px = pp - py * P;
    int y = py - 1, x = px - 1;
    i8 v = 0;
    const bool inside = (unsigned)y < (unsigned)Dout && (unsigned)x < (unsigned)Dout;
    if (op == 0) {
        if (inside) {
            const float* G = (g1[0] >= 32.0f) ? g1 : g2;
            const float* B = (g1[0] >= 32.0f) ? g2 : g1;
            double m = mu[c], r = rs[c];
            double g = (double)G[t * 256 + c];
            double b = (double)B[t * 256 + c];
            double iv = (double)invv[0];
            int Din = Dout << 1;
            int ib = (((n * Din + 2 * y) * Din) + 2 * x) << 8;
            int rowstr = Din << 8;
            int k0 = a[ib + c], k1 = a[ib + 256 + c];
            int k2 = a[ib + rowstr + c], k3 = a[ib + rowstr + 256 + c];
            int km = k0 > k1 ? k0 : k1;
            if (k2 > km) km = k2;
            if (k3 > km) km = k3;
            double bn = g * (((double)km * (1.0 / 262144.0) - m) * r) + b;
            v = (i8)(int)trunc(bn * iv);
        }
        bq_out[((size_t)sp << 8) + c] = v;
    } else {
        const i8* in = (op == 1) ? pi1 : (op == 2 ? pi2 : pi3);
        i8* out = (op == 1) ? po1 : (op == 2 ? po2 : po3);
        if (inside) {
            int PIN = 2 * Dout + 2;
            int ib = ((n * PIN + 2 * y + 1) * PIN + 2 * x + 1) << 8;
            int rowstr = PIN << 8;
            int a0 = in[ib + c], a1 = in[ib + 256 + c];
            int a2 = in[ib + rowstr + c], a3 = in[ib + rowstr + 256 + c];
            int m2 = a0 > a1 ? a0 : a1;
            if (a2 > m2) m2 = a2;
            if (a3 > m2) m2 = a3;
            v = (i8)m2;
        }
        out[((size_t)sp << 8) + c] = v;
    }
}

// fused: spatial max (8x8, padded in) + linear
__global__ void featlin_kernel(const i8* __restrict__ a9, const float* __restrict__ lw,
                               const float* __restrict__ lb, float* __restrict__ out) {
    __shared__ float fsh[256];
    int n = blockIdx.x, c = threadIdx.x;
    int mx = -1000;
    for (int r = 0; r < 64; r++) {
        int y = r >> 3, x = r & 7;
        int v = a9[(((n * 100 + (y + 1) * 10 + x + 1)) << 8) + c];
        if (v > mx) mx = v;
    }
    fsh[c] = (float)mx * (1.0f / 64.0f);
    __syncthreads();
    for (int k = c; k < 1000; k += 256) {
        float acc = lb[k];
        const float* wr = lw + k * 256;
        for (int cc = 0; cc < 256; cc++) acc = fmaf(fsh[cc], wr[cc], acc);
        out[n * 1000 + k] = acc;
    }
}

extern "C" void kernel_launch(void* const* d_in, const int* in_sizes, int n_in,
                              void* d_out, int out_size, void* d_ws, size_t ws_size,
                              hipStream_t stream) {
    const float *xin = 0, *conv_w = 0, *lin_w = 0, *lin_b = 0, *alphas = 0, *gb1 = 0, *gb2 = 0;
    for (int i = 0; i < n_in; i++) {
        const float* p = (const float*)d_in[i];
        switch (in_sizes[i]) {
            case 393216: xin = p; break;
            case 589824: conv_w = p; break;
            case 256000: lin_w = p; break;
            case 1000:   lin_b = p; break;
            case 60:     alphas = p; break;
            case 2560:   if (!gb1) gb1 = p; else gb2 = p; break;
            default: break;
        }
    }

    char* ws = (char*)d_ws;
    const size_t FRSZ = 35684352ull;                // 32*66*66*256
    const size_t SSSZ = 9469952ull;                 // 32*34*34*256
    i8* FR[3];
    for (int i = 0; i < 3; i++) FR[i] = (i8*)(ws + (size_t)i * FRSZ);
    char* AP = ws + 3 * FRSZ;
    int* a_pre = (int*)AP;
    i8* SS[7];
    for (int i = 0; i < 6; i++) SS[i] = (i8*)(AP + 33554432ull + (size_t)i * SSSZ);
    SS[6] = (i8*)(ws + 3 * FRSZ + 134217728ull);
    i8* wt = (i8*)((char*)SS[6] + SSSZ);
    size_t off = (size_t)(((char*)wt - ws)) + 589824ull;
    ull*      s1g  = (ull*)(ws + off);      off += 327680;
    ull*      s2g  = (ull*)(ws + off);      off += 327680;
    int*      kmng = (int*)(ws + off);      off += 163840;
    int*      kmxg = (int*)(ws + off);      off += 163840;
    double*   mu   = (double*)(ws + off);   off += 2048;
    double*   rs   = (double*)(ws + off);   off += 2048;
    float*    invv = (float*)(ws + off);    off += 256;
    unsigned* ctr  = (unsigned*)(ws + off); off += 256;
    const size_t need = off;

    if (!xin || !conv_w || !lin_w || !lin_b || !alphas || !gb1 || !gb2) {
        fill_kernel<<<(out_size + 255) / 256, 256, 0, stream>>>((float*)d_out, out_size, 1792.0f);
        return;
    }
    if (ws_size < need) {
        float sv = 1000.0f + (float)(ws_size >> 20);
        fill_kernel<<<(out_size + 255) / 256, 256, 0, stream>>>((float*)d_out, out_size, sv);
        return;
    }

    setup_kernel<<<9016, 256, 0, stream>>>(conv_w, wt, xin, FR[0], s1g, s2g, kmng, kmxg, ctr);

    auto conv_part = [&](int t, int D, i8* actp, i8* p0, i8* p1, i8* p2, i8* p3, int nh) {
        int logW = __builtin_ctz(D);
        int M = 32 * D * D;
        int G = (M / 128) * 2;
        int nA = (D == 64) ? 5 : (D == 16 ? 3 : 4);
        switch (nh) {
            case 1: conv_kernel<1><<<G, 256, 0, stream>>>(actp, wt, a_pre, p0, p1, p2, p3,
                        alphas, t, D, logW, D + 2, nA, M, gb1, gb2,
                        s1g, s2g, kmng, kmxg, mu, rs, invv, ctr); break;
            case 2: conv_kernel<2><<<G, 256, 0, stream>>>(actp, wt, a_pre, p0, p1, p2, p3,
                        alphas, t, D, logW, D + 2, nA, M, gb1, gb2,
                        s1g, s2g, kmng, kmxg, mu, rs, invv, ctr); break;
            case 3: conv_kernel<3><<<G, 256, 0, stream>>>(actp, wt, a_pre, p0, p1, p2, p3,
                        alphas, t, D, logW, D + 2, nA, M, gb1, gb2,
                        s1g, s2g, kmng, kmxg, mu, rs, invv, ctr); break;
            default: conv_kernel<4><<<G, 256, 0, stream>>>(actp, wt, a_pre, p0, p1, p2, p3,
                        alphas, t, D, logW, D + 2, nA, M, gb1, gb2,
                        s1g, s2g, kmng, kmxg, mu, rs, invv, ctr); break;
        }
    };
    auto bnq_part = [&](int t, int D, i8* outp) {
        int PW = D + 2;
        bnq_kernel<<<32 * PW * PW, 256, 0, stream>>>(a_pre, outp, mu, rs, gb1, gb2, t, invv,
                                                     D, __builtin_ctz(D), PW);
    };
    auto combo_part = [&](int t, int Dout, i8* bqout,
                          i8* i1, i8* o1, i8* i2, i8* o2, i8* i3, i8* o3) {
        int P = Dout + 2;
        poolcombo_kernel<<<dim3(32 * P * P, 4), 256, 0, stream>>>(
            a_pre, bqout, i1, o1, i2, o2, i3, o3, mu, rs, gb1, gb2, t, invv, Dout);
    };

    // t=0..2 @64
    conv_part(0, 64, FR[0], FR[0], FR[0], FR[0], FR[0], 1);
    bnq_part(0, 64, FR[1]);                                   // a0
    conv_part(1, 64, FR[1], FR[0], FR[1], FR[1], FR[1], 2);
    bnq_part(1, 64, FR[2]);                                   // a1
    conv_part(2, 64, FR[2], FR[0], FR[1], FR[2], FR[2], 3);
    // a2@32 -> SS6 ; x0p->SS0, a0p->SS1, a1p->SS2
    combo_part(2, 32, SS[6], FR[0], SS[0], FR[1], SS[1], FR[2], SS[2]);
    // t=3..5 @32
    conv_part(3, 32, SS[6], SS[0], SS[1], SS[2], SS[6], 4);
    bnq_part(3, 32, SS[3]);                                   // a3
    conv_part(4, 32, SS[3], SS[1], SS[2], SS[6], SS[3], 4);
    bnq_part(4, 32, SS[4]);                                   // a4
    conv_part(5, 32, SS[4], SS[2], SS[6], SS[3], SS[4], 4);
    // a5@16 -> SS5 ; a2@16: SS6->SS0, a3@16: SS3->SS1, a4@16: SS4->SS2
    combo_part(5, 16, SS[5], SS[6], SS[0], SS[3], SS[1], SS[4], SS[2]);
    // t=6..8 @16
    conv_part(6, 16, SS[5], SS[0], SS[1], SS[2], SS[5], 4);
    bnq_part(6, 16, SS[3]);                                   // a6
    conv_part(7, 16, SS[3], SS[1], SS[2], SS[5], SS[3], 4);
    bnq_part(7, 16, SS[4]);                                   // a7
    conv_part(8, 16, SS[4], SS[2], SS[5], SS[3], SS[4], 4);
    // a8@8 -> SS6 ; a5@8: SS5->SS0, a6@8: SS3->SS1, a7@8: SS4->SS2
    combo_part(8, 8, SS[6], SS[5], SS[0], SS[3], SS[1], SS[4], SS[2]);
    // t=9 @8
    conv_part(9, 8, SS[6], SS[0], SS[1], SS[2], SS[6], 4);
    bnq_part(9, 8, SS[3]);                                    // a9

    featlin_kernel<<<32, 256, 0, stream>>>(SS[3], lin_w, lin_b, (float*)d_out);
}

// Round 18
// 1034.006 us; speedup vs baseline: 1.2583x; 1.2583x over previous
//
#include <hip/hip_runtime.h>
#include <hip/hip_bf16.h>

// R18: revert R17's conv-fused finalize (per-block __threadfence = L2
// writeback per block -> 133->210us regression). conv + separate finalize =
// exact R15 hot path. KEEP the validated merges: setup (wt+qx+stats) and
// poolcombo (bnqpool + 3 pools in one launch). 32 launches total.

typedef unsigned short u16;
typedef signed char i8;
typedef unsigned long long ull;
typedef long long ll;
typedef int i32x4 __attribute__((ext_vector_type(4)));

__device__ __forceinline__ void glds16(const i8* g, i8* l) {
    __builtin_amdgcn_global_load_lds(
        (const __attribute__((address_space(1))) void*)g,
        (__attribute__((address_space(3))) void*)l, 16, 0, 0);
}

__global__ void fill_kernel(float* __restrict__ out, int n, float v) {
    int i = blockIdx.x * 256 + threadIdx.x;
    if (i < n) out[i] = v;
}

// merged setup: wt (blocks 0..143), qx (144..8855), stats init (8856..9015)
__global__ void setup_kernel(const float* __restrict__ w, i8* __restrict__ wt,
                             const float* __restrict__ x, i8* __restrict__ qout,
                             ull* s1, ull* s2, int* kmn, int* kmx) {
    int b = blockIdx.x;
    int tid = threadIdx.x;
    if (b < 144) {
        int g = b * 256 + tid;                      // 36864 groups of 16
        int base = g * 16;
        int ci0 = base & 255;
        int co  = (base >> 8) & 255;
        int tap = base >> 16;
        i8 tmp[16];
#pragma unroll
        for (int j = 0; j < 16; j++)
            tmp[j] = (i8)__builtin_rintf(w[((co << 8) + ci0 + j) * 9 + tap] * 64.0f);
        *(uint4*)(wt + base) = *(const uint4*)tmp;
    } else if (b < 8856) {
        int g = (b - 144) * 256 + tid;              // halo-padded 66x66 qx
        int chunk = g & 15;
        int p = g >> 4;
        i8 tmp[16];
#pragma unroll
        for (int j = 0; j < 16; j++) tmp[j] = 0;
        if (chunk == 0) {
            int n  = p / 4356;
            int pp = p - n * 4356;
            int py = pp / 66;
            int px = pp - py * 66;
            if (py >= 1 && py <= 64 && px >= 1 && px <= 64) {
                int yx = ((py - 1) << 6) + (px - 1);
#pragma unroll
                for (int c = 0; c < 3; c++)
                    tmp[c] = (i8)truncf(x[((n * 3 + c) << 12) + yx] * (1.0f / 64.0f));
            }
        }
        *(uint4*)(qout + (size_t)g * 16) = *(const uint4*)tmp;
    } else {
        int i = (b - 8856) * 256 + tid;             // 40960 stat slots
        s1[i] = 0ull; s2[i] = 0ull;
        kmn[i] = 0x7fffffff; kmx[i] = -0x7fffffff - 1;
    }
}

// conv 3x3 implicit GEMM, i8 MFMA K=64; A halo-band + 3-tap B groups (R15).
template<int NH>
__global__ __launch_bounds__(256) void conv_kernel(
    const i8* __restrict__ act, const i8* __restrict__ wtp, int* __restrict__ a_pre,
    const i8* __restrict__ h0, const i8* __restrict__ h1,
    const i8* __restrict__ h2, const i8* __restrict__ h3,
    const float* __restrict__ alphas, int t,
    int W, int logW, int PW, int nA,
    ull* __restrict__ s1g, ull* __restrict__ s2g,
    int* __restrict__ kmng, int* __restrict__ kmxg)
{
    __shared__ __align__(16) i8 As[320 * 64];      // A halo band (one ci-chunk)
    __shared__ __align__(16) i8 Bs[3 * 128 * 64];  // B, 3 taps
    const int tid  = threadIdx.x;
    const int G    = gridDim.x;
    const int d    = blockIdx.x;
    const int sw   = (d & 7) * (G >> 3) + (d >> 3);   // XCD-contiguous
    const int m0   = (sw >> 1) * 128;
    const int c0   = (sw & 1) * 128;
    const int lane = tid & 63;
    const int wv   = tid >> 6;
    const int wm   = (wv & 1) * 64;
    const int wn   = (wv >> 1) * 64;
    const int l15  = lane & 15;
    const int quad = lane >> 4;
    const int logHW = 2 * logW;
    const int HW   = W * W;
    const int PP   = PW * PW;

    i32x4 acc[4][4];
#pragma unroll
    for (int i = 0; i < 4; i++)
#pragma unroll
        for (int j = 0; j < 4; j++) acc[i][j] = (i32x4){0, 0, 0, 0};

    const int n0 = m0 >> logHW;
    const int y0 = (m0 & (HW - 1)) >> logW;
    const long bandstart = (long)n0 * PP + (long)y0 * PW;

    int pb[4];
#pragma unroll
    for (int i = 0; i < 4; i++) {
        int mr = m0 + wm + i * 16 + l15;
        int nn = mr >> logHW;
        int rr = mr & (HW - 1);
        pb[i] = (nn - n0) * PP + ((rr >> logW) - y0 + 1) * PW + (rr & (W - 1)) + 1;
    }

    const int qrow = tid >> 2;                      // 0..63
    const int bb   = (tid & 3) * 16;
    i8* const ldsbaseA = As + wv * 1024 + lane * 16;
    const int ko = quad * 16;

    for (int chunk = 0; chunk < 4; ++chunk) {
        const int cb = chunk * 64;
#pragma unroll
        for (int g = 0; g < 3; ++g) {
            __syncthreads();                        // prev readers done
            if (g == 0) {
                for (int k = 0; k < nA; ++k)        // stage A band
                    glds16(act + (bandstart + qrow + k * 64) * 256 + cb + bb,
                           ldsbaseA + k * 4096);
            }
#pragma unroll
            for (int tt = 0; tt < 3; ++tt) {        // stage B taps 3g..3g+2
                const int tap = 3 * g + tt;
#pragma unroll
                for (int p = 0; p < 2; ++p)
                    glds16(wtp + (tap << 16) + ((c0 + qrow + p * 64) << 8) + cb + bb,
                           Bs + tt * 8192 + wv * 1024 + p * 4096 + lane * 16);
            }
            __syncthreads();                        // DMA drained
#pragma unroll
            for (int tt = 0; tt < 3; ++tt) {
                const int tap = 3 * g + tt;
                const int dY  = tap / 3 - 1;
                const int dX  = tap % 3 - 1;
                const int uoff = dY * PW + dX;
                i32x4 bf[4];
#pragma unroll
                for (int j = 0; j < 4; j++)
                    bf[j] = *(const i32x4*)(&Bs[tt * 8192 + (wn + j * 16 + l15) * 64 + ko]);
#pragma unroll
                for (int i = 0; i < 4; i++) {
                    i32x4 af = *(const i32x4*)(&As[(pb[i] + uoff) * 64 + ko]);
#pragma unroll
                    for (int j = 0; j < 4; j++)
                        acc[i][j] = __builtin_amdgcn_mfma_i32_16x16x64_i8(af, bf[j], acc[i][j], 0, 0, 0);
                }
            }
        }
    }

    // slim epilogue: a_k = a0k*relu(K) + 64*sum(aqk*hk)
    const int a0k = (int)__builtin_rintf(alphas[t * 6] * 64.0f);
    int aq64[NH];
    const i8* hp[4] = {h0, h1, h2, h3};
#pragma unroll
    for (int q = 0; q < NH; q++)
        aq64[q] = (int)__builtin_rintf(alphas[t * 6 + (6 - NH) + q] * 64.0f) * 64;

    const int shard = sw & 15;
#pragma unroll
    for (int j = 0; j < 4; j++) {
        const int cg = c0 + wn + j * 16 + l15;
        ll s1 = 0, s2 = 0;
        int mn = 0x7fffffff, mx = -0x7fffffff - 1;
#pragma unroll
        for (int i = 0; i < 4; i++) {
            const int mo0 = m0 + wm + i * 16 + quad * 4;
            const int n   = mo0 >> logHW;
            const int rem = mo0 & (HW - 1);
            const int yy  = rem >> logW;
            const int xx  = rem & (W - 1);
            const int phb = (((n * PW + yy + 1) * PW) + xx + 1) << 8;
#pragma unroll
            for (int r = 0; r < 4; r++) {
                const int idx  = ((mo0 + r) << 8) + cg;
                const int pidx = phb + (r << 8) + cg;
                int K = acc[i][j][r];
                int av = a0k * (K > 0 ? K : 0);
#pragma unroll
                for (int q = 0; q < NH; q++) av += aq64[q] * (int)hp[q][pidx];
                a_pre[idx] = av;
                s1 += av;
                s2 += (ll)av * (ll)av;
                mn = av < mn ? av : mn;
                mx = av > mx ? av : mx;
            }
        }
        s1 += __shfl_xor(s1, 16); s1 += __shfl_xor(s1, 32);
        s2 += __shfl_xor(s2, 16); s2 += __shfl_xor(s2, 32);
        int o;
        o = __shfl_xor(mn, 16); mn = o < mn ? o : mn;
        o = __shfl_xor(mn, 32); mn = o < mn ? o : mn;
        o = __shfl_xor(mx, 16); mx = o > mx ? o : mx;
        o = __shfl_xor(mx, 32); mx = o > mx ? o : mx;
        if (quad == 0) {
            const int sidx = shard * 2560 + t * 256 + cg;
            atomicAdd(&s1g[sidx], (ull)s1);
            atomicAdd(&s2g[sidx], (ull)s2);
            atomicMin(&kmng[sidx], mn);
            atomicMax(&kmxg[sidx], mx);
        }
    }
}

__global__ void finalize_kernel(const ull* __restrict__ s1g, const ull* __restrict__ s2g,
                                const int* __restrict__ kmng, const int* __restrict__ kmxg,
                                const float* __restrict__ g1, const float* __restrict__ g2,
                                int t, int M, double* mu_o, double* rs_o, float* invv) {
    __shared__ float red[256];
    int c = threadIdx.x;
    const float* G = (g1[0] >= 32.0f) ? g1 : g2;
    const float* B = (g1[0] >= 32.0f) ? g2 : g1;
    ll S1i = 0, S2i = 0;
    int kmn = 0x7fffffff, kmx = -0x7fffffff - 1;
    for (int sh = 0; sh < 16; sh++) {
        int sidx = sh * 2560 + t * 256 + c;
        S1i += (ll)s1g[sidx];
        S2i += (ll)s2g[sidx];
        int a = kmng[sidx]; kmn = a < kmn ? a : kmn;
        int b2 = kmxg[sidx]; kmx = b2 > kmx ? b2 : kmx;
    }
    double S1 = (double)S1i;
    double S2 = (double)S2i;
    double Md = (double)M;
    double mu = S1 / (Md * 262144.0);
    double var = (S2 - S1 * S1 / Md) / (Md * 68719476736.0);
    if (var < 0.0) var = 0.0;
    double rs = 1.0 / sqrt(var + 1e-5);
    mu_o[c] = mu; rs_o[c] = rs;
    double g = (double)G[t * 256 + c];
    double b = (double)B[t * 256 + c];
    double lo = (double)kmn * (1.0 / 262144.0);
    double hi = (double)kmx * (1.0 / 262144.0);
    double bnlo = g * ((lo - mu) * rs) + b;
    double bnhi = g * ((hi - mu) * rs) + b;
    red[c] = (float)fmax(fabs(bnlo), fabs(bnhi));
    __syncthreads();
    for (int s = 128; s > 0; s >>= 1) {
        if (c < s) red[c] = fmaxf(red[c], red[c + s]);
        __syncthreads();
    }
    if (c == 0) invv[0] = (red[0] < 1.0f) ? (1.0f / 128.0f) : (1.0f / 64.0f);
}

// BN apply + quantize -> padded int8 (halo = 0); dense a_pre in
__global__ void bnq_kernel(const int* __restrict__ a, i8* __restrict__ out,
                           const double* __restrict__ mu, const double* __restrict__ rs,
                           const float* __restrict__ g1, const float* __restrict__ g2,
                           int t, const float* __restrict__ invv,
                           int W, int logW, int PW) {
    int c = threadIdx.x;
    int sp = blockIdx.x;
    int PP = PW * PW;
    int n  = sp / PP;
    int pp = sp - n * PP;
    int py = pp / PW;
    int px = pp - py * PW;
    int y = py - 1, x = px - 1;
    i8 v = 0;
    if ((unsigned)y < (unsigned)W && (unsigned)x < (unsigned)W) {
        const float* G = (g1[0] >= 32.0f) ? g1 : g2;
        const float* B = (g1[0] >= 32.0f) ? g2 : g1;
        double m = mu[c], r = rs[c];
        double g = (double)G[t * 256 + c];
        double b = (double)B[t * 256 + c];
        double iv = (double)invv[0];
        int idx = (((n << logW) + y) << logW << 8) + (x << 8) + c;
        double bn = g * (((double)a[idx] * (1.0 / 262144.0) - m) * r) + b;
        v = (i8)(int)trunc(bn * iv);
    }
    out[((size_t)sp << 8) + c] = v;
}

// merged pool step: grid.y==0 -> fused BN+quantize+2x2maxpool (a_pre -> bq_out);
// grid.y==1..3 -> plain 2x2 maxpool (pi -> po). All padded layout (halo=0).
__global__ void poolcombo_kernel(const int* __restrict__ a, i8* __restrict__ bq_out,
                                 const i8* __restrict__ pi1, i8* __restrict__ po1,
                                 const i8* __restrict__ pi2, i8* __restrict__ po2,
                                 const i8* __restrict__ pi3, i8* __restrict__ po3,
                                 const double* __restrict__ mu, const double* __restrict__ rs,
                                 const float* __restrict__ g1, const float* __restrict__ g2,
                                 int t, const float* __restrict__ invv, int Dout) {
    int c = threadIdx.x;
    int sp = blockIdx.x;
    int op = blockIdx.y;
    int P = Dout + 2;
    int PP = P * P;
    int n  = sp / PP;
    int pp = sp - n * PP;
    int py = pp / P;
    int px = pp - py * P;
    int y = py - 1, x = px - 1;
    i8 v = 0;
    const bool inside = (unsigned)y < (unsigned)Dout && (unsigned)x < (unsigned)Dout;
    if (op == 0) {
        if (inside) {
            const float* G = (g1[0] >= 32.0f) ? g1 : g2;
            const float* B = (g1[0] >= 32.0f) ? g2 : g1;
            double m = mu[c], r = rs[c];
            double g = (double)G[t * 256 + c];
            double b = (double)B[t * 256 + c];
            double iv = (double)invv[0];
            int Din = Dout << 1;
            int ib = (((n * Din + 2 * y) * Din) + 2 * x) << 8;
            int rowstr = Din << 8;
            int k0 = a[ib + c], k1 = a[ib + 256 + c];
            int k2 = a[ib + rowstr + c], k3 = a[ib + rowstr + 256 + c];
            int km = k0 > k1 ? k0 : k1;
            if (k2 > km) km = k2;
            if (k3 > km) km = k3;
            double bn = g * (((double)km * (1.0 / 262144.0) - m) * r) + b;
            v = (i8)(int)trunc(bn * iv);
        }
        bq_out[((size_t)sp << 8) + c] = v;
    } else {
        const i8* in = (op == 1) ? pi1 : (op == 2 ? pi2 : pi3);
        i8* out = (op == 1) ? po1 : (op == 2 ? po2 : po3);
        if (inside) {
            int PIN = 2 * Dout + 2;
            int ib = ((n * PIN + 2 * y + 1) * PIN + 2 * x + 1) << 8;
            int rowstr = PIN << 8;
            int a0 = in[ib + c], a1 = in[ib + 256 + c];
            int a2 = in[ib + rowstr + c], a3 = in[ib + rowstr + 256 + c];
            int m2 = a0 > a1 ? a0 : a1;
            if (a2 > m2) m2 = a2;
            if (a3 > m2) m2 = a3;
            v = (i8)m2;
        }
        out[((size_t)sp << 8) + c] = v;
    }
}

// fused: spatial max (8x8, padded in) + linear
__global__ void featlin_kernel(const i8* __restrict__ a9, const float* __restrict__ lw,
                               const float* __restrict__ lb, float* __restrict__ out) {
    __shared__ float fsh[256];
    int n = blockIdx.x, c = threadIdx.x;
    int mx = -1000;
    for (int r = 0; r < 64; r++) {
        int y = r >> 3, x = r & 7;
        int v = a9[(((n * 100 + (y + 1) * 10 + x + 1)) << 8) + c];
        if (v > mx) mx = v;
    }
    fsh[c] = (float)mx * (1.0f / 64.0f);
    __syncthreads();
    for (int k = c; k < 1000; k += 256) {
        float acc = lb[k];
        const float* wr = lw + k * 256;
        for (int cc = 0; cc < 256; cc++) acc = fmaf(fsh[cc], wr[cc], acc);
        out[n * 1000 + k] = acc;
    }
}

extern "C" void kernel_launch(void* const* d_in, const int* in_sizes, int n_in,
                              void* d_out, int out_size, void* d_ws, size_t ws_size,
                              hipStream_t stream) {
    const float *xin = 0, *conv_w = 0, *lin_w = 0, *lin_b = 0, *alphas = 0, *gb1 = 0, *gb2 = 0;
    for (int i = 0; i < n_in; i++) {
        const float* p = (const float*)d_in[i];
        switch (in_sizes[i]) {
            case 393216: xin = p; break;
            case 589824: conv_w = p; break;
            case 256000: lin_w = p; break;
            case 1000:   lin_b = p; break;
            case 60:     alphas = p; break;
            case 2560:   if (!gb1) gb1 = p; else gb2 = p; break;
            default: break;
        }
    }

    char* ws = (char*)d_ws;
    const size_t FRSZ = 35684352ull;                // 32*66*66*256
    const size_t SSSZ = 9469952ull;                 // 32*34*34*256
    i8* FR[3];
    for (int i = 0; i < 3; i++) FR[i] = (i8*)(ws + (size_t)i * FRSZ);
    char* AP = ws + 3 * FRSZ;
    int* a_pre = (int*)AP;
    i8* SS[7];
    for (int i = 0; i < 6; i++) SS[i] = (i8*)(AP + 33554432ull + (size_t)i * SSSZ);
    SS[6] = (i8*)(ws + 3 * FRSZ + 134217728ull);
    i8* wt = (i8*)((char*)SS[6] + SSSZ);
    size_t off = (size_t)(((char*)wt - ws)) + 589824ull;
    ull*    s1g  = (ull*)(ws + off);    off += 327680;
    ull*    s2g  = (ull*)(ws + off);    off += 327680;
    int*    kmng = (int*)(ws + off);    off += 163840;
    int*    kmxg = (int*)(ws + off);    off += 163840;
    double* mu   = (double*)(ws + off); off += 2048;
    double* rs   = (double*)(ws + off); off += 2048;
    float*  invv = (float*)(ws + off);  off += 256;
    const size_t need = off;

    if (!xin || !conv_w || !lin_w || !lin_b || !alphas || !gb1 || !gb2) {
        fill_kernel<<<(out_size + 255) / 256, 256, 0, stream>>>((float*)d_out, out_size, 1792.0f);
        return;
    }
    if (ws_size < need) {
        float sv = 1000.0f + (float)(ws_size >> 20);
        fill_kernel<<<(out_size + 255) / 256, 256, 0, stream>>>((float*)d_out, out_size, sv);
        return;
    }

    setup_kernel<<<9016, 256, 0, stream>>>(conv_w, wt, xin, FR[0], s1g, s2g, kmng, kmxg);

    auto conv_part = [&](int t, int D, i8* actp, i8* p0, i8* p1, i8* p2, i8* p3, int nh) {
        int logW = __builtin_ctz(D);
        int M = 32 * D * D;
        int G = (M / 128) * 2;
        int nA = (D == 64) ? 5 : (D == 16 ? 3 : 4);
        switch (nh) {
            case 1: conv_kernel<1><<<G, 256, 0, stream>>>(actp, wt, a_pre, p0, p1, p2, p3,
                        alphas, t, D, logW, D + 2, nA, s1g, s2g, kmng, kmxg); break;
            case 2: conv_kernel<2><<<G, 256, 0, stream>>>(actp, wt, a_pre, p0, p1, p2, p3,
                        alphas, t, D, logW, D + 2, nA, s1g, s2g, kmng, kmxg); break;
            case 3: conv_kernel<3><<<G, 256, 0, stream>>>(actp, wt, a_pre, p0, p1, p2, p3,
                        alphas, t, D, logW, D + 2, nA, s1g, s2g, kmng, kmxg); break;
            default: conv_kernel<4><<<G, 256, 0, stream>>>(actp, wt, a_pre, p0, p1, p2, p3,
                        alphas, t, D, logW, D + 2, nA, s1g, s2g, kmng, kmxg); break;
        }
        finalize_kernel<<<1, 256, 0, stream>>>(s1g, s2g, kmng, kmxg, gb1, gb2, t, M, mu, rs, invv);
    };
    auto bnq_part = [&](int t, int D, i8* outp) {
        int PW = D + 2;
        bnq_kernel<<<32 * PW * PW, 256, 0, stream>>>(a_pre, outp, mu, rs, gb1, gb2, t, invv,
                                                     D, __builtin_ctz(D), PW);
    };
    auto combo_part = [&](int t, int Dout, i8* bqout,
                          i8* i1, i8* o1, i8* i2, i8* o2, i8* i3, i8* o3) {
        int P = Dout + 2;
        poolcombo_kernel<<<dim3(32 * P * P, 4), 256, 0, stream>>>(
            a_pre, bqout, i1, o1, i2, o2, i3, o3, mu, rs, gb1, gb2, t, invv, Dout);
    };

    // t=0..2 @64
    conv_part(0, 64, FR[0], FR[0], FR[0], FR[0], FR[0], 1);
    bnq_part(0, 64, FR[1]);                                   // a0
    conv_part(1, 64, FR[1], FR[0], FR[1], FR[1], FR[1], 2);
    bnq_part(1, 64, FR[2]);                                   // a1
    conv_part(2, 64, FR[2], FR[0], FR[1], FR[2], FR[2], 3);
    // a2@32 -> SS6 ; x0p->SS0, a0p->SS1, a1p->SS2
    combo_part(2, 32, SS[6], FR[0], SS[0], FR[1], SS[1], FR[2], SS[2]);
    // t=3..5 @32
    conv_part(3, 32, SS[6], SS[0], SS[1], SS[2], SS[6], 4);
    bnq_part(3, 32, SS[3]);                                   // a3
    conv_part(4, 32, SS[3], SS[1], SS[2], SS[6], SS[3], 4);
    bnq_part(4, 32, SS[4]);                                   // a4
    conv_part(5, 32, SS[4], SS[2], SS[6], SS[3], SS[4], 4);
    // a5@16 -> SS5 ; a2@16: SS6->SS0, a3@16: SS3->SS1, a4@16: SS4->SS2
    combo_part(5, 16, SS[5], SS[6], SS[0], SS[3], SS[1], SS[4], SS[2]);
    // t=6..8 @16
    conv_part(6, 16, SS[5], SS[0], SS[1], SS[2], SS[5], 4);
    bnq_part(6, 16, SS[3]);                                   // a6
    conv_part(7, 16, SS[3], SS[1], SS[2], SS[5], SS[3], 4);
    bnq_part(7, 16, SS[4]);                                   // a7
    conv_part(8, 16, SS[4], SS[2], SS[5], SS[3], SS[4], 4);
    // a8@8 -> SS6 ; a5@8: SS5->SS0, a6@8: SS3->SS1, a7@8: SS4->SS2
    combo_part(8, 8, SS[6], SS[5], SS[0], SS[3], SS[1], SS[4], SS[2]);
    // t=9 @8
    conv_part(9, 8, SS[6], SS[0], SS[1], SS[2], SS[6], 4);
    bnq_part(9, 8, SS[3]);                                    // a9

    featlin_kernel<<<32, 256, 0, stream>>>(SS[3], lin_w, lin_b, (float*)d_out);
}